// Round 1
// baseline (409.029 us; speedup 1.0000x reference)
//
#include <hip/hip_runtime.h>
#include <math.h>

#define NB 64
#define CC 512
#define LL 256
#define TILE 64
#define BK 16

// -------------------- Kernel 1: compaction + row norms + zeroing --------------------
__global__ __launch_bounds__(256) void prep_kernel(
    const float* __restrict__ S, const float* __restrict__ T,
    const int* __restrict__ targets,
    int* __restrict__ idx, int* __restrict__ npos,
    float* __restrict__ rn_s, float* __restrict__ rn_t,
    float* __restrict__ sum_s, float* __restrict__ sum_t,
    float* __restrict__ out)
{
    const int n = blockIdx.x;
    const int tid = threadIdx.x;
    __shared__ int s_idx[CC];
    __shared__ int s_np;
    if (tid == 0) {
        sum_s[n] = 0.0f;
        sum_t[n] = 0.0f;
        if (n == 0) out[0] = 0.0f;
        int cnt = 0;
        const int* tg = targets + n * CC;
        for (int c = 0; c < CC; ++c) if (tg[c] != 0) s_idx[cnt++] = c;
        s_np = cnt;
        npos[n] = cnt;
    }
    __syncthreads();
    const int np = s_np;
    for (int k = tid; k < np; k += 256) idx[n * CC + k] = s_idx[k];

    // one wave per compacted row: 64 lanes x float4 == 256 floats == L
    const int wave = tid >> 6, lane = tid & 63;
    for (int k = wave; k < np; k += 4) {
        const int r = s_idx[k];
        const float4 a = ((const float4*)(S + ((size_t)n * CC + r) * LL))[lane];
        const float4 b = ((const float4*)(T + ((size_t)n * CC + r) * LL))[lane];
        float vs = a.x * a.x + a.y * a.y + a.z * a.z + a.w * a.w;
        float vt = b.x * b.x + b.y * b.y + b.z * b.z + b.w * b.w;
        #pragma unroll
        for (int o = 32; o > 0; o >>= 1) {
            vs += __shfl_down(vs, o);
            vt += __shfl_down(vt, o);
        }
        if (lane == 0) {
            rn_s[n * CC + k] = vs;
            rn_t[n * CC + k] = vt;
        }
    }
}

// -------------------- Kernels 2/3: tiled pairwise distances --------------------
// PASS 1: accumulate sum of distances (student & teacher) over off-diag positive pairs.
// PASS 2: recompute distances, Huber(d/mean_s - td/mean_t), accumulate into out.
template <int PASS>
__global__ __launch_bounds__(256) void dist_kernel(
    const float* __restrict__ S, const float* __restrict__ T,
    const int* __restrict__ idx, const int* __restrict__ npos,
    const float* __restrict__ rn_s, const float* __restrict__ rn_t,
    float* __restrict__ sum_s, float* __restrict__ sum_t,
    float* __restrict__ out)
{
    const int n  = blockIdx.z;
    const int tI = blockIdx.y;
    const int tJ = blockIdx.x;
    if (tJ < tI) return;               // symmetric: upper triangle only
    const int np = npos[n];
    if (np < 2) return;                // invalid batch contributes 0
    if (tI * TILE >= np || tJ * TILE >= np) return;

    __shared__ float As[BK][TILE], Bs[BK][TILE], At[BK][TILE], Bt[BK][TILE];
    __shared__ int rowI[TILE], rowJ[TILE];
    __shared__ float red0[4], red1[4];

    const int tid = threadIdx.x;
    if (tid < TILE) {
        const int gi = tI * TILE + tid;
        rowI[tid] = (gi < np) ? idx[n * CC + gi] : idx[n * CC];
    } else if (tid < 2 * TILE) {
        const int t2 = tid - TILE;
        const int gj = tJ * TILE + t2;
        rowJ[t2] = (gj < np) ? idx[n * CC + gj] : idx[n * CC];
    }
    __syncthreads();

    const int lr = tid >> 2;            // 0..63 (row within tile for loading)
    const int lk = (tid & 3) * 4;       // k offset within BK chunk
    const int tx = tid & 15, ty = tid >> 4;

    const float* Sp = S + (size_t)n * CC * LL;
    const float* Tp = T + (size_t)n * CC * LL;
    const int rI = rowI[lr], rJ = rowJ[lr];

    float accS[4][4] = {{0}}, accT[4][4] = {{0}};

    for (int kk = 0; kk < LL; kk += BK) {
        const float4 a = *(const float4*)(Sp + (size_t)rI * LL + kk + lk);
        const float4 b = *(const float4*)(Sp + (size_t)rJ * LL + kk + lk);
        const float4 c = *(const float4*)(Tp + (size_t)rI * LL + kk + lk);
        const float4 d = *(const float4*)(Tp + (size_t)rJ * LL + kk + lk);
        __syncthreads();   // previous iteration's reads done
        As[lk + 0][lr] = a.x; As[lk + 1][lr] = a.y; As[lk + 2][lr] = a.z; As[lk + 3][lr] = a.w;
        Bs[lk + 0][lr] = b.x; Bs[lk + 1][lr] = b.y; Bs[lk + 2][lr] = b.z; Bs[lk + 3][lr] = b.w;
        At[lk + 0][lr] = c.x; At[lk + 1][lr] = c.y; At[lk + 2][lr] = c.z; At[lk + 3][lr] = c.w;
        Bt[lk + 0][lr] = d.x; Bt[lk + 1][lr] = d.y; Bt[lk + 2][lr] = d.z; Bt[lk + 3][lr] = d.w;
        __syncthreads();
        #pragma unroll
        for (int k = 0; k < BK; ++k) {
            const float4 aS = *(const float4*)(&As[k][ty * 4]);
            const float4 bS = *(const float4*)(&Bs[k][tx * 4]);
            const float4 aT = *(const float4*)(&At[k][ty * 4]);
            const float4 bT = *(const float4*)(&Bt[k][tx * 4]);
            const float as_[4] = {aS.x, aS.y, aS.z, aS.w};
            const float bs_[4] = {bS.x, bS.y, bS.z, bS.w};
            const float at_[4] = {aT.x, aT.y, aT.z, aT.w};
            const float bt_[4] = {bT.x, bT.y, bT.z, bT.w};
            #pragma unroll
            for (int i = 0; i < 4; ++i)
                #pragma unroll
                for (int j = 0; j < 4; ++j) {
                    accS[i][j] = fmaf(as_[i], bs_[j], accS[i][j]);
                    accT[i][j] = fmaf(at_[i], bt_[j], accT[i][j]);
                }
        }
    }

    // ------- epilogue -------
    float rnIs[4], rnJs[4], rnIt[4], rnJt[4];
    #pragma unroll
    for (int i = 0; i < 4; ++i) {
        const int gi = tI * TILE + ty * 4 + i;
        rnIs[i] = (gi < np) ? rn_s[n * CC + gi] : 0.0f;
        rnIt[i] = (gi < np) ? rn_t[n * CC + gi] : 0.0f;
    }
    #pragma unroll
    for (int j = 0; j < 4; ++j) {
        const int gj = tJ * TILE + tx * 4 + j;
        rnJs[j] = (gj < np) ? rn_s[n * CC + gj] : 0.0f;
        rnJt[j] = (gj < np) ? rn_t[n * CC + gj] : 0.0f;
    }

    float inv_ms = 0.0f, inv_mt = 0.0f;
    if (PASS == 2) {
        const float cnt = (float)np * (float)(np - 1);
        inv_ms = cnt / sum_s[n];   // 1/mean_s
        inv_mt = cnt / sum_t[n];   // 1/mean_t
    }

    float loc0 = 0.0f, loc1 = 0.0f;
    #pragma unroll
    for (int i = 0; i < 4; ++i) {
        const int gi = tI * TILE + ty * 4 + i;
        #pragma unroll
        for (int j = 0; j < 4; ++j) {
            const int gj = tJ * TILE + tx * 4 + j;
            if (gi < np && gj < np && gi != gj) {
                const float d2s = rnIs[i] + rnJs[j] - 2.0f * accS[i][j];
                const float ds  = sqrtf(fmaxf(d2s, 1e-12f));
                const float d2t = rnIt[i] + rnJt[j] - 2.0f * accT[i][j];
                const float dt  = sqrtf(fmaxf(d2t, 1e-12f));
                if (PASS == 1) {
                    loc0 += ds;
                    loc1 += dt;
                } else {
                    const float diff  = ds * inv_ms - dt * inv_mt;
                    const float adiff = fabsf(diff);
                    loc0 += (adiff < 1.0f) ? 0.5f * diff * diff : adiff - 0.5f;
                }
            }
        }
    }

    // block reduction
    #pragma unroll
    for (int o = 32; o > 0; o >>= 1) {
        loc0 += __shfl_down(loc0, o);
        if (PASS == 1) loc1 += __shfl_down(loc1, o);
    }
    const int wave = tid >> 6, lane = tid & 63;
    __syncthreads();
    if (lane == 0) { red0[wave] = loc0; red1[wave] = (PASS == 1) ? loc1 : 0.0f; }
    __syncthreads();
    if (tid == 0) {
        const float w = (tI == tJ) ? 1.0f : 2.0f;   // symmetric tiles counted twice
        const float t0 = red0[0] + red0[1] + red0[2] + red0[3];
        if (PASS == 1) {
            const float t1 = red1[0] + red1[1] + red1[2] + red1[3];
            atomicAdd(&sum_s[n], w * t0);
            atomicAdd(&sum_t[n], w * t1);
        } else {
            atomicAdd(out, w * t0 / (float)np);
        }
    }
}

extern "C" void kernel_launch(void* const* d_in, const int* in_sizes, int n_in,
                              void* d_out, int out_size, void* d_ws, size_t ws_size,
                              hipStream_t stream) {
    const float* S = (const float*)d_in[0];
    const float* T = (const float*)d_in[1];
    const int* targets = (const int*)d_in[2];
    float* out = (float*)d_out;

    // workspace layout
    int* idx = (int*)d_ws;                   // NB*CC
    int* npos = idx + NB * CC;               // NB
    float* rn_s = (float*)(npos + NB);       // NB*CC
    float* rn_t = rn_s + NB * CC;            // NB*CC
    float* sum_s = rn_t + NB * CC;           // NB
    float* sum_t = sum_s + NB;               // NB

    prep_kernel<<<NB, 256, 0, stream>>>(S, T, targets, idx, npos, rn_s, rn_t,
                                        sum_s, sum_t, out);

    dim3 grid(CC / TILE, CC / TILE, NB);     // (tJ, tI, n); inactive tiles exit early
    dist_kernel<1><<<grid, 256, 0, stream>>>(S, T, idx, npos, rn_s, rn_t,
                                             sum_s, sum_t, out);
    dist_kernel<2><<<grid, 256, 0, stream>>>(S, T, idx, npos, rn_s, rn_t,
                                             sum_s, sum_t, out);
}

// Round 2
// 171.487 us; speedup vs baseline: 2.3852x; 2.3852x over previous
//
#include <hip/hip_runtime.h>
#include <hip/hip_bf16.h>
#include <math.h>

#define NB 64
#define CC 512
#define LL 256

typedef __attribute__((ext_vector_type(4))) float floatx4;
typedef __attribute__((ext_vector_type(8))) short short8;

static __device__ __forceinline__ unsigned f2bf2(float x, float y) {
    __hip_bfloat162 h = __float22bfloat162_rn(make_float2(x, y));
    union { __hip_bfloat162 h; unsigned u; } cvt;
    cvt.h = h;
    return cvt.u;
}

// -------------------- Kernel 1: parallel compaction + zeroing --------------------
// Order of compacted indices does not matter: all downstream sums are
// permutation-invariant over the set of positive rows.
__global__ __launch_bounds__(256) void compact_kernel(
    const int* __restrict__ targets,
    int* __restrict__ idx, int* __restrict__ npos,
    float* __restrict__ sum_s, float* __restrict__ sum_t,
    float* __restrict__ out)
{
    const int n = blockIdx.x, tid = threadIdx.x;
    __shared__ int s_np;
    if (tid == 0) {
        s_np = 0;
        sum_s[n] = 0.0f;
        sum_t[n] = 0.0f;
        if (n == 0) out[0] = 0.0f;
    }
    __syncthreads();
    for (int c = tid; c < CC; c += 256)
        if (targets[n * CC + c] != 0) {
            int p = atomicAdd(&s_np, 1);
            idx[n * CC + p] = c;
        }
    __syncthreads();
    if (tid == 0) npos[n] = s_np;
}

// -------------------- Kernel 2: row squared-norms (compacted rows) --------------------
__global__ __launch_bounds__(256) void norms_kernel(
    const float* __restrict__ S, const float* __restrict__ T,
    const int* __restrict__ idx, const int* __restrict__ npos,
    float* __restrict__ rn_s, float* __restrict__ rn_t)
{
    const int n = blockIdx.y, g = blockIdx.x;
    const int np = npos[n];
    const int tid = threadIdx.x, w = tid >> 6, lane = tid & 63;
    const int kend = min(np, (g + 1) * 64);
    for (int k = g * 64 + w; k < kend; k += 4) {
        const int r = idx[n * CC + k];
        const float4 a = ((const float4*)(S + ((size_t)n * CC + r) * LL))[lane];
        const float4 b = ((const float4*)(T + ((size_t)n * CC + r) * LL))[lane];
        float vs = a.x * a.x + a.y * a.y + a.z * a.z + a.w * a.w;
        float vt = b.x * b.x + b.y * b.y + b.z * b.z + b.w * b.w;
        #pragma unroll
        for (int o = 32; o; o >>= 1) { vs += __shfl_down(vs, o); vt += __shfl_down(vt, o); }
        if (lane == 0) { rn_s[n * CC + k] = vs; rn_t[n * CC + k] = vt; }
    }
}

// -------------------- Kernels 3/4: MFMA pairwise-distance tiles --------------------
// PASS 1: accumulate sum of off-diag positive-pair distances (student & teacher).
// PASS 2: recompute distances, Huber(d/mean_s - td/mean_t), accumulate to out.
template <int PASS>
__global__ __launch_bounds__(256) void dist_kernel(
    const float* __restrict__ S, const float* __restrict__ T,
    const int* __restrict__ idx, const int* __restrict__ npos,
    const float* __restrict__ rn_s, const float* __restrict__ rn_t,
    float* __restrict__ sum_s, float* __restrict__ sum_t,
    float* __restrict__ out)
{
    const int n = blockIdx.y;
    // linear id -> upper-triangular (tI, tJ) of the 8x8 tile grid
    int tI = 0, rem = blockIdx.x;
    while (rem >= 8 - tI) { rem -= 8 - tI; ++tI; }
    const int tJ = tI + rem;

    const int np = npos[n];
    if (np < 2) return;
    if (tI * 64 >= np || tJ * 64 >= np) return;
    const bool diag = (tI == tJ);

    // bf16 tiles, row stride 40 (pad 8) to spread LDS banks; 16B-aligned rows (80 B)
    __shared__ __align__(16) unsigned short lds[4][64][40];
    __shared__ float red0[4], red1[4];

    const int tid = threadIdx.x;
    const int w = tid >> 6, lane = tid & 63;

    // ---- staging assignment: wave w stages buffer w ----
    // buf0 = A rows of S, buf1 = B rows of S, buf2 = A rows of T, buf3 = B rows of T
    const bool stager = (!diag) || ((w & 1) == 0);
    const float* Pbase = ((w >> 1) ? T : S) + (size_t)n * CC * LL;
    const int tileBase = ((w & 1) ? tJ : tI) * 64;
    const int r8 = lane >> 3, c8 = lane & 7;   // 8 lanes per row, 128B contiguous
    const float* base_[8];
    #pragma unroll
    for (int i = 0; i < 8; ++i) {
        const int gk = tileBase + r8 + 8 * i;
        const int row = idx[n * CC + (gk < np ? gk : 0)];
        base_[i] = Pbase + (size_t)row * LL + c8 * 4;
    }

    float4 pre[8];
    if (stager) {
        #pragma unroll
        for (int i = 0; i < 8; ++i) pre[i] = *(const float4*)(base_[i]);
    }

    const int m16 = lane & 15, quad = lane >> 4;
    const unsigned short* As_ = &lds[0][0][0];
    const unsigned short* Bs_ = diag ? &lds[0][0][0] : &lds[1][0][0];
    const unsigned short* At_ = &lds[2][0][0];
    const unsigned short* Bt_ = diag ? &lds[2][0][0] : &lds[3][0][0];

    floatx4 accS[4], accT[4];
    #pragma unroll
    for (int c = 0; c < 4; ++c)
        #pragma unroll
        for (int r = 0; r < 4; ++r) { accS[c][r] = 0.0f; accT[c][r] = 0.0f; }

    const int wrow = w * 16;   // this wave's 16-row strip of the 64-row tile
    for (int kk = 0; kk < 8; ++kk) {
        __syncthreads();   // previous MFMA reads complete
        if (stager) {
            #pragma unroll
            for (int i = 0; i < 8; ++i) {
                unsigned* dst = (unsigned*)&lds[w][r8 + 8 * i][c8 * 4];
                dst[0] = f2bf2(pre[i].x, pre[i].y);
                dst[1] = f2bf2(pre[i].z, pre[i].w);
            }
        }
        __syncthreads();
        if (stager && kk < 7) {        // prefetch next chunk during MFMA
            #pragma unroll
            for (int i = 0; i < 8; ++i)
                pre[i] = *(const float4*)(base_[i] + (kk + 1) * 32);
        }
        const int aoff = (wrow + m16) * 40 + quad * 8;
        const short8 a_s = *(const short8*)(As_ + aoff);
        const short8 a_t = *(const short8*)(At_ + aoff);
        #pragma unroll
        for (int c = 0; c < 4; ++c) {
            const int boff = (c * 16 + m16) * 40 + quad * 8;
            const short8 b_s = *(const short8*)(Bs_ + boff);
            const short8 b_t = *(const short8*)(Bt_ + boff);
            accS[c] = __builtin_amdgcn_mfma_f32_16x16x32_bf16(a_s, b_s, accS[c], 0, 0, 0);
            accT[c] = __builtin_amdgcn_mfma_f32_16x16x32_bf16(a_t, b_t, accT[c], 0, 0, 0);
        }
    }

    // ---- epilogue: C/D layout col=lane&15, row=quad*4+reg ----
    const int giBase = tI * 64 + wrow + quad * 4;
    float rnIs[4], rnIt[4];
    #pragma unroll
    for (int r = 0; r < 4; ++r) {
        const int gi = giBase + r;
        const bool v = gi < np;
        rnIs[r] = v ? rn_s[n * CC + gi] : 0.0f;
        rnIt[r] = v ? rn_t[n * CC + gi] : 0.0f;
    }
    float rnJs[4], rnJt[4];
    #pragma unroll
    for (int c = 0; c < 4; ++c) {
        const int gj = tJ * 64 + c * 16 + m16;
        const bool v = gj < np;
        rnJs[c] = v ? rn_s[n * CC + gj] : 0.0f;
        rnJt[c] = v ? rn_t[n * CC + gj] : 0.0f;
    }

    float inv_ms = 0.0f, inv_mt = 0.0f;
    if (PASS == 2) {
        const float cnt = (float)np * (float)(np - 1);
        inv_ms = cnt / sum_s[n];
        inv_mt = cnt / sum_t[n];
    }

    float l0 = 0.0f, l1 = 0.0f;
    #pragma unroll
    for (int c = 0; c < 4; ++c) {
        const int gj = tJ * 64 + c * 16 + m16;
        #pragma unroll
        for (int r = 0; r < 4; ++r) {
            const int gi = giBase + r;
            if (gi < np && gj < np && gi != gj) {
                const float ds = sqrtf(fmaxf(rnIs[r] + rnJs[c] - 2.0f * accS[c][r], 1e-12f));
                const float dt = sqrtf(fmaxf(rnIt[r] + rnJt[c] - 2.0f * accT[c][r], 1e-12f));
                if (PASS == 1) { l0 += ds; l1 += dt; }
                else {
                    const float diff = ds * inv_ms - dt * inv_mt;
                    const float ad = fabsf(diff);
                    l0 += (ad < 1.0f) ? 0.5f * diff * diff : ad - 0.5f;
                }
            }
        }
    }

    #pragma unroll
    for (int o = 32; o; o >>= 1) {
        l0 += __shfl_down(l0, o);
        if (PASS == 1) l1 += __shfl_down(l1, o);
    }
    __syncthreads();
    if (lane == 0) { red0[w] = l0; red1[w] = (PASS == 1) ? l1 : 0.0f; }
    __syncthreads();
    if (tid == 0) {
        const float wgt = diag ? 1.0f : 2.0f;   // symmetric: off-diag tiles counted twice
        const float t0 = red0[0] + red0[1] + red0[2] + red0[3];
        if (PASS == 1) {
            const float t1 = red1[0] + red1[1] + red1[2] + red1[3];
            atomicAdd(&sum_s[n], wgt * t0);
            atomicAdd(&sum_t[n], wgt * t1);
        } else {
            atomicAdd(out, wgt * t0 / (float)np);
        }
    }
}

extern "C" void kernel_launch(void* const* d_in, const int* in_sizes, int n_in,
                              void* d_out, int out_size, void* d_ws, size_t ws_size,
                              hipStream_t stream) {
    const float* S = (const float*)d_in[0];
    const float* T = (const float*)d_in[1];
    const int* targets = (const int*)d_in[2];
    float* out = (float*)d_out;

    int* idx = (int*)d_ws;                   // NB*CC
    int* npos = idx + NB * CC;               // NB
    float* rn_s = (float*)(npos + NB);       // NB*CC
    float* rn_t = rn_s + NB * CC;            // NB*CC
    float* sum_s = rn_t + NB * CC;           // NB
    float* sum_t = sum_s + NB;               // NB

    compact_kernel<<<NB, 256, 0, stream>>>(targets, idx, npos, sum_s, sum_t, out);
    norms_kernel<<<dim3(8, NB), 256, 0, stream>>>(S, T, idx, npos, rn_s, rn_t);

    dim3 grid(36, NB);   // upper-triangular 8x8 tile pairs
    dist_kernel<1><<<grid, 256, 0, stream>>>(S, T, idx, npos, rn_s, rn_t,
                                             sum_s, sum_t, out);
    dist_kernel<2><<<grid, 256, 0, stream>>>(S, T, idx, npos, rn_s, rn_t,
                                             sum_s, sum_t, out);
}

// Round 3
// 159.913 us; speedup vs baseline: 2.5578x; 1.0724x over previous
//
#include <hip/hip_runtime.h>
#include <hip/hip_bf16.h>
#include <math.h>

#define NB 64
#define CC 512
#define LL 256

typedef __attribute__((ext_vector_type(4))) float floatx4;
typedef __attribute__((ext_vector_type(8))) short short8;

static __device__ __forceinline__ unsigned f2bf2(float x, float y) {
    __hip_bfloat162 h = __float22bfloat162_rn(make_float2(x, y));
    union { __hip_bfloat162 h; unsigned u; } cvt;
    cvt.h = h;
    return cvt.u;
}

// -------------------- Kernel 1: parallel compaction + zeroing --------------------
// Order of compacted indices does not matter: all downstream reductions are
// permutation-invariant over the set of positive rows (validity tests use only
// position < np, which is permutation-independent).
__global__ __launch_bounds__(256) void compact_kernel(
    const int* __restrict__ targets,
    int* __restrict__ idx, int* __restrict__ npos,
    float* __restrict__ sum_s, float* __restrict__ sum_t,
    float* __restrict__ out)
{
    const int n = blockIdx.x, tid = threadIdx.x;
    __shared__ int s_np;
    if (tid == 0) {
        s_np = 0;
        sum_s[n] = 0.0f;
        sum_t[n] = 0.0f;
        if (n == 0) out[0] = 0.0f;
    }
    __syncthreads();
    for (int c = tid; c < CC; c += 256)
        if (targets[n * CC + c] != 0) {
            int p = atomicAdd(&s_np, 1);
            idx[n * CC + p] = c;
        }
    __syncthreads();
    if (tid == 0) npos[n] = s_np;
}

// -------------------- Kernel 2: row squared-norms (compacted rows) --------------------
__global__ __launch_bounds__(256) void norms_kernel(
    const float* __restrict__ S, const float* __restrict__ T,
    const int* __restrict__ idx, const int* __restrict__ npos,
    float* __restrict__ rn_s, float* __restrict__ rn_t)
{
    const int n = blockIdx.y, g = blockIdx.x;
    const int np = npos[n];
    const int tid = threadIdx.x, w = tid >> 6, lane = tid & 63;
    const int kend = min(np, (g + 1) * 64);
    for (int k = g * 64 + w; k < kend; k += 4) {
        const int r = idx[n * CC + k];
        const float4 a = ((const float4*)(S + ((size_t)n * CC + r) * LL))[lane];
        const float4 b = ((const float4*)(T + ((size_t)n * CC + r) * LL))[lane];
        float vs = a.x * a.x + a.y * a.y + a.z * a.z + a.w * a.w;
        float vt = b.x * b.x + b.y * b.y + b.z * b.z + b.w * b.w;
        #pragma unroll
        for (int o = 32; o; o >>= 1) { vs += __shfl_down(vs, o); vt += __shfl_down(vt, o); }
        if (lane == 0) { rn_s[n * CC + k] = vs; rn_t[n * CC + k] = vt; }
    }
}

// -------------------- Kernel 3: MFMA pairwise distances, stored to D --------------------
// Computes ds/dt for its 64x64 tile, stores (ds, dt) as float2, and accumulates the
// per-batch off-diagonal distance sums via atomics.
__global__ __launch_bounds__(256) void dist_kernel(
    const float* __restrict__ S, const float* __restrict__ T,
    const int* __restrict__ idx, const int* __restrict__ npos,
    const float* __restrict__ rn_s, const float* __restrict__ rn_t,
    float* __restrict__ sum_s, float* __restrict__ sum_t,
    float2* __restrict__ D)
{
    const int n = blockIdx.y;
    int tI = 0, rem = blockIdx.x;                 // linear -> upper-tri (tI, tJ)
    while (rem >= 8 - tI) { rem -= 8 - tI; ++tI; }
    const int tJ = tI + rem;

    const int np = npos[n];
    if (np < 2) return;
    if (tI * 64 >= np || tJ * 64 >= np) return;
    const bool diag = (tI == tJ);

    // bf16 tiles, double-buffered chunks. Row stride 40 (pad 8); rows 80 B (16B-aligned).
    __shared__ __align__(16) unsigned short lds[4][2][64][40];   // 40 KiB
    __shared__ float red0[4], red1[4];

    const int tid = threadIdx.x;
    const int w = tid >> 6, lane = tid & 63;

    // wave w stages buffer w: 0=S-A, 1=S-B, 2=T-A, 3=T-B (diag: B aliases A)
    const bool stager = (!diag) || ((w & 1) == 0);
    const float* Pbase = ((w >> 1) ? T : S) + (size_t)n * CC * LL;
    const int tileBase = ((w & 1) ? tJ : tI) * 64;
    const int r8 = lane >> 3, c8 = lane & 7;      // 8 lanes per row, 128 B contiguous
    const float* base_[8];
    #pragma unroll
    for (int i = 0; i < 8; ++i) {
        const int gk = tileBase + r8 + 8 * i;
        const int row = idx[n * CC + (gk < np ? gk : 0)];
        base_[i] = Pbase + (size_t)row * LL + c8 * 4;
    }

    float4 pre[8];
    if (stager) {
        #pragma unroll
        for (int i = 0; i < 8; ++i) pre[i] = *(const float4*)(base_[i]);
    }

    const int m16 = lane & 15, quad = lane >> 4;
    const int bufB = diag ? 0 : 1;                 // B aliases A on diagonal tiles

    floatx4 accS[4], accT[4];
    #pragma unroll
    for (int c = 0; c < 4; ++c)
        #pragma unroll
        for (int r = 0; r < 4; ++r) { accS[c][r] = 0.0f; accT[c][r] = 0.0f; }

    const int wrow = w * 16;
    for (int kk = 0; kk < 8; ++kk) {
        const int pb = kk & 1;
        if (stager) {
            #pragma unroll
            for (int i = 0; i < 8; ++i) {
                uint2* dst = (uint2*)&lds[w][pb][r8 + 8 * i][c8 * 4];
                *dst = make_uint2(f2bf2(pre[i].x, pre[i].y), f2bf2(pre[i].z, pre[i].w));
            }
            if (kk < 7) {
                #pragma unroll
                for (int i = 0; i < 8; ++i)
                    pre[i] = *(const float4*)(base_[i] + (kk + 1) * 32);
            }
        }
        __syncthreads();   // writes to buf pb visible; prior reads of pb finished last iter
        const int aoff = (wrow + m16) * 40 + quad * 8;
        const short8 a_s = *(const short8*)(&lds[0][pb][0][0] + aoff);
        const short8 a_t = *(const short8*)(&lds[2][pb][0][0] + aoff);
        #pragma unroll
        for (int c = 0; c < 4; ++c) {
            const int boff = (c * 16 + m16) * 40 + quad * 8;
            const short8 b_s = *(const short8*)(&lds[bufB][pb][0][0] + boff);
            const short8 b_t = *(const short8*)(&lds[2 + bufB][pb][0][0] + boff);
            accS[c] = __builtin_amdgcn_mfma_f32_16x16x32_bf16(a_s, b_s, accS[c], 0, 0, 0);
            accT[c] = __builtin_amdgcn_mfma_f32_16x16x32_bf16(a_t, b_t, accT[c], 0, 0, 0);
        }
        __syncthreads();   // all reads of buf pb done before next write to it (kk+2)
    }

    // ---- epilogue: C/D layout col=lane&15, row=quad*4+reg ----
    const int liBase = wrow + quad * 4;            // local row in tile
    const int giBase = tI * 64 + liBase;
    float rnIs[4], rnIt[4];
    #pragma unroll
    for (int r = 0; r < 4; ++r) {
        const int gi = giBase + r;
        const bool v = gi < np;
        rnIs[r] = v ? rn_s[n * CC + gi] : 0.0f;
        rnIt[r] = v ? rn_t[n * CC + gi] : 0.0f;
    }
    float rnJs[4], rnJt[4];
    #pragma unroll
    for (int c = 0; c < 4; ++c) {
        const int gj = tJ * 64 + c * 16 + m16;
        const bool v = gj < np;
        rnJs[c] = v ? rn_s[n * CC + gj] : 0.0f;
        rnJt[c] = v ? rn_t[n * CC + gj] : 0.0f;
    }

    float2* Dn = D + (((size_t)n * 36 + blockIdx.x) << 12);   // 64x64 entries
    float l0 = 0.0f, l1 = 0.0f;
    #pragma unroll
    for (int c = 0; c < 4; ++c) {
        const int lj = c * 16 + m16;
        const int gj = tJ * 64 + lj;
        #pragma unroll
        for (int r = 0; r < 4; ++r) {
            const int gi = giBase + r;
            const float ds = sqrtf(fmaxf(rnIs[r] + rnJs[c] - 2.0f * accS[c][r], 1e-12f));
            const float dt = sqrtf(fmaxf(rnIt[r] + rnJt[c] - 2.0f * accT[c][r], 1e-12f));
            Dn[(liBase + r) * 64 + lj] = make_float2(ds, dt);
            if (gi < np && gj < np && gi != gj) { l0 += ds; l1 += dt; }
        }
    }

    #pragma unroll
    for (int o = 32; o; o >>= 1) { l0 += __shfl_down(l0, o); l1 += __shfl_down(l1, o); }
    __syncthreads();
    if (lane == 0) { red0[w] = l0; red1[w] = l1; }
    __syncthreads();
    if (tid == 0) {
        const float wgt = diag ? 1.0f : 2.0f;      // off-diag tiles mirror-counted
        atomicAdd(&sum_s[n], wgt * (red0[0] + red0[1] + red0[2] + red0[3]));
        atomicAdd(&sum_t[n], wgt * (red1[0] + red1[1] + red1[2] + red1[3]));
    }
}

// -------------------- Kernel 4: streaming Huber reduce over stored D --------------------
__global__ __launch_bounds__(256) void huber_kernel(
    const float2* __restrict__ D,
    const int* __restrict__ npos,
    const float* __restrict__ sum_s, const float* __restrict__ sum_t,
    float* __restrict__ out)
{
    const int n = blockIdx.y;
    int tI = 0, rem = blockIdx.x;
    while (rem >= 8 - tI) { rem -= 8 - tI; ++tI; }
    const int tJ = tI + rem;

    const int np = npos[n];
    if (np < 2) return;
    if (tI * 64 >= np || tJ * 64 >= np) return;

    const float cnt = (float)np * (float)(np - 1);
    const float inv_ms = cnt / sum_s[n];
    const float inv_mt = cnt / sum_t[n];

    const float2* Dn = D + (((size_t)n * 36 + blockIdx.x) << 12);
    const int tid = threadIdx.x;

    float l0 = 0.0f;
    #pragma unroll
    for (int e = tid; e < 4096; e += 256) {
        const int gi = tI * 64 + (e >> 6);
        const int gj = tJ * 64 + (e & 63);
        if (gi < np && gj < np && gi != gj) {
            const float2 v = Dn[e];
            const float diff = v.x * inv_ms - v.y * inv_mt;
            const float ad = fabsf(diff);
            l0 += (ad < 1.0f) ? 0.5f * diff * diff : ad - 0.5f;
        }
    }

    #pragma unroll
    for (int o = 32; o; o >>= 1) l0 += __shfl_down(l0, o);
    __shared__ float red[4];
    const int w = tid >> 6, lane = tid & 63;
    __syncthreads();
    if (lane == 0) red[w] = l0;
    __syncthreads();
    if (tid == 0) {
        const float wgt = (tI == tJ) ? 1.0f : 2.0f;
        atomicAdd(out, wgt * (red[0] + red[1] + red[2] + red[3]) / (float)np);
    }
}

extern "C" void kernel_launch(void* const* d_in, const int* in_sizes, int n_in,
                              void* d_out, int out_size, void* d_ws, size_t ws_size,
                              hipStream_t stream) {
    const float* S = (const float*)d_in[0];
    const float* T = (const float*)d_in[1];
    const int* targets = (const int*)d_in[2];
    float* out = (float*)d_out;

    int* idx = (int*)d_ws;                   // NB*CC ints
    int* npos = idx + NB * CC;               // NB
    float* rn_s = (float*)(npos + NB);       // NB*CC
    float* rn_t = rn_s + NB * CC;            // NB*CC
    float* sum_s = rn_t + NB * CC;           // NB
    float* sum_t = sum_s + NB;               // NB
    // D: align to 256 B, NB*36*4096 float2 = 75.5 MB (ws is ~268 MB)
    size_t off = ((size_t)((char*)(sum_t + NB) - (char*)d_ws) + 255) & ~(size_t)255;
    float2* D = (float2*)((char*)d_ws + off);

    compact_kernel<<<NB, 256, 0, stream>>>(targets, idx, npos, sum_s, sum_t, out);
    norms_kernel<<<dim3(8, NB), 256, 0, stream>>>(S, T, idx, npos, rn_s, rn_t);

    dim3 grid(36, NB);   // upper-triangular 8x8 tile pairs
    dist_kernel<<<grid, 256, 0, stream>>>(S, T, idx, npos, rn_s, rn_t,
                                          sum_s, sum_t, D);
    huber_kernel<<<grid, 256, 0, stream>>>(D, npos, sum_s, sum_t, out);
}